// Round 12
// baseline (151.057 us; speedup 1.0000x reference)
//
#include <hip/hip_runtime.h>
#include <hip/hip_bf16.h>

// Shapes (fixed): B=4, H=56, W=56, C=256, NH=8, HD=32, KS=7, PAD=3
// tokens M = 4*56*56 = 12544. Padded k/v planes: [4][64][64][256] bf16,
// interior token (y,x) at plane row y+3, col x+3; border zeroed by prep.

using frag_ab = __attribute__((ext_vector_type(8))) short;  // 8 bf16 (4 VGPRs)
using f32x4   = __attribute__((ext_vector_type(4))) float;  // 4 fp32 acc

__device__ __forceinline__ float bflo(unsigned int u) { return __uint_as_float(u << 16); }
__device__ __forceinline__ float bfhi(unsigned int u) { return __uint_as_float(u & 0xffff0000u); }

// ================= fused prep =================
// blocks [0,3136):    x fp32 -> xb bf16 (float4/thread)
// blocks [3136,3904): w_qkv [256][768] -> wqkvT [768][256] bf16
// blocks [3904,4160): w_proj [256][256] -> wprojT [256][256] bf16
// blocks [4160,5120): zero the 960 border cols of each padded plane
__global__ __launch_bounds__(256) void prep(
    const float* __restrict__ x,      __hip_bfloat16* __restrict__ xb,
    const float* __restrict__ w_qkv,  __hip_bfloat16* __restrict__ wqkvT,
    const float* __restrict__ w_proj, __hip_bfloat16* __restrict__ wprojT,
    __hip_bfloat16* __restrict__ kp,  __hip_bfloat16* __restrict__ vp)
{
    const int bid = blockIdx.x;
    const int tid = threadIdx.x;
    if (bid < 3136) {
        const int i = bid * 256 + tid;            // over M*256/4 = 802816
        const float4 v = ((const float4*)x)[i];
        union { ushort4 u; __hip_bfloat16 h[4]; } o;
        o.h[0] = __float2bfloat16(v.x); o.h[1] = __float2bfloat16(v.y);
        o.h[2] = __float2bfloat16(v.z); o.h[3] = __float2bfloat16(v.w);
        ((ushort4*)xb)[i] = o.u;
    } else if (bid < 3904) {
        const int idx = (bid - 3136) * 256 + tid; // over 768*256
        const int k = idx & 255, n = idx >> 8;
        wqkvT[idx] = __float2bfloat16(w_qkv[k * 768 + n]);
    } else if (bid < 4160) {
        const int idx = (bid - 3904) * 256 + tid; // over 256*256
        const int k = idx & 255, n = idx >> 8;
        wprojT[idx] = __float2bfloat16(w_proj[k * 256 + n]);
    } else {
        const int u    = (bid - 4160) * 256 + tid;   // over 8*30720
        const int ip   = u / 30720;                  // img*2 + plane
        const int rem  = u - ip * 30720;
        const int cloc = rem >> 5;                   // 0..959 border cells
        const int q16  = rem & 31;                   // 16B chunk of 256 ch
        const int img  = ip >> 1;
        __hip_bfloat16* base = (ip & 1) ? vp : kp;
        int prow, pcol;
        if (cloc < 512) {                            // full pad rows 0-2,59-63
            const int r8 = cloc >> 6;
            prow = (r8 < 3) ? r8 : r8 + 56;
            pcol = cloc & 63;
        } else {                                     // side pads of rows 3..58
            const int c2 = cloc - 512;
            prow = 3 + (c2 >> 3);
            const int cc = c2 & 7;
            pcol = (cc < 3) ? cc : cc + 56;
        }
        *(uint4*)(base + (((size_t)(img * 64 + prow)) * 64 + pcol) * 256 + q16 * 8) =
            make_uint4(0u, 0u, 0u, 0u);
    }
}

// ================= LDS-free direct-fragment bf16 MFMA GEMM =================
// Both operands are row-major [row][256] and the 16x16x32 fragment is 16 B
// contiguous per lane (row = lane&15, k-chunk = (lane>>4)*8), so each wave
// loads its 4 A-frags + 4 B-frags per K-step with global_load_dwordx4 straight
// into VGPRs: NO LDS, NO __syncthreads (K=256 is too shallow to amortize the
// 16 barrier drains of the staged 128-tile version). Two-stage pipeline with
// NAMED frag registers (R10 lesson: pointer-captured arrays defeat SROA ->
// scratch); rolled outer loop (R8/R9 lesson: full unroll hoists all loads ->
// 256-VGPR spill). Liveness ~140 VGPR. Block = 256 thr = 4 waves, wave w owns
// quadrant (w>>1, w&1) of the 128x128 tile as 4x4 16x16 frags. Duplicate
// global reads (2x A, 2x B per block) are L2-absorbed.
#define LOADF8(koff, A0, A1, A2, A3, B0, B1, B2, B3)                            \
    do {                                                                        \
        const char* pa_ = (const char*)gA + (size_t)(koff) * 2;                 \
        const char* pb_ = (const char*)gB + (size_t)(koff) * 2;                 \
        A0 = *(const frag_ab*)(pa_);                                            \
        A1 = *(const frag_ab*)(pa_ + 8192);    /* +16 rows * 512 B */           \
        A2 = *(const frag_ab*)(pa_ + 16384);                                    \
        A3 = *(const frag_ab*)(pa_ + 24576);                                    \
        B0 = *(const frag_ab*)(pb_);                                            \
        B1 = *(const frag_ab*)(pb_ + 8192);                                     \
        B2 = *(const frag_ab*)(pb_ + 16384);                                    \
        B3 = *(const frag_ab*)(pb_ + 24576);                                    \
    } while (0)

#define MFMA16(A0, A1, A2, A3, B0, B1, B2, B3)                                  \
    do {                                                                        \
        acc[0][0] = __builtin_amdgcn_mfma_f32_16x16x32_bf16(A0, B0, acc[0][0], 0, 0, 0); \
        acc[0][1] = __builtin_amdgcn_mfma_f32_16x16x32_bf16(A0, B1, acc[0][1], 0, 0, 0); \
        acc[0][2] = __builtin_amdgcn_mfma_f32_16x16x32_bf16(A0, B2, acc[0][2], 0, 0, 0); \
        acc[0][3] = __builtin_amdgcn_mfma_f32_16x16x32_bf16(A0, B3, acc[0][3], 0, 0, 0); \
        acc[1][0] = __builtin_amdgcn_mfma_f32_16x16x32_bf16(A1, B0, acc[1][0], 0, 0, 0); \
        acc[1][1] = __builtin_amdgcn_mfma_f32_16x16x32_bf16(A1, B1, acc[1][1], 0, 0, 0); \
        acc[1][2] = __builtin_amdgcn_mfma_f32_16x16x32_bf16(A1, B2, acc[1][2], 0, 0, 0); \
        acc[1][3] = __builtin_amdgcn_mfma_f32_16x16x32_bf16(A1, B3, acc[1][3], 0, 0, 0); \
        acc[2][0] = __builtin_amdgcn_mfma_f32_16x16x32_bf16(A2, B0, acc[2][0], 0, 0, 0); \
        acc[2][1] = __builtin_amdgcn_mfma_f32_16x16x32_bf16(A2, B1, acc[2][1], 0, 0, 0); \
        acc[2][2] = __builtin_amdgcn_mfma_f32_16x16x32_bf16(A2, B2, acc[2][2], 0, 0, 0); \
        acc[2][3] = __builtin_amdgcn_mfma_f32_16x16x32_bf16(A2, B3, acc[2][3], 0, 0, 0); \
        acc[3][0] = __builtin_amdgcn_mfma_f32_16x16x32_bf16(A3, B0, acc[3][0], 0, 0, 0); \
        acc[3][1] = __builtin_amdgcn_mfma_f32_16x16x32_bf16(A3, B1, acc[3][1], 0, 0, 0); \
        acc[3][2] = __builtin_amdgcn_mfma_f32_16x16x32_bf16(A3, B2, acc[3][2], 0, 0, 0); \
        acc[3][3] = __builtin_amdgcn_mfma_f32_16x16x32_bf16(A3, B3, acc[3][3], 0, 0, 0); \
    } while (0)

#define GEMM_DIRECT_BODY(EPILOGUE)                                              \
    constexpr int K = 256;                                                      \
    const int tid  = threadIdx.x;                                               \
    const int lane = tid & 63;                                                  \
    const int w    = tid >> 6;                                                  \
    const int wm   = w >> 1, wn = w & 1;                                        \
    const int m0 = blockIdx.y * 128;                                            \
    const int n0 = blockIdx.x * 128;                                            \
    const __hip_bfloat16* gA =                                                  \
        A  + (size_t)(m0 + wm * 64 + (lane & 15)) * K + (lane >> 4) * 8;        \
    const __hip_bfloat16* gB =                                                  \
        BT + (size_t)(n0 + wn * 64 + (lane & 15)) * K + (lane >> 4) * 8;        \
    f32x4 acc[4][4] = {};                                                       \
    frag_ab xa0, xa1, xa2, xa3, xb0, xb1, xb2, xb3;  /* stage X */              \
    frag_ab ya0, ya1, ya2, ya3, yb0, yb1, yb2, yb3;  /* stage Y */              \
    LOADF8(0,  xa0, xa1, xa2, xa3, xb0, xb1, xb2, xb3);                         \
    LOADF8(32, ya0, ya1, ya2, ya3, yb0, yb1, yb2, yb3);                         \
    _Pragma("unroll 1")                                                         \
    for (int kk = 0; kk < 3; ++kk) {                                            \
        MFMA16(xa0, xa1, xa2, xa3, xb0, xb1, xb2, xb3);                         \
        LOADF8(kk * 64 + 64, xa0, xa1, xa2, xa3, xb0, xb1, xb2, xb3);           \
        MFMA16(ya0, ya1, ya2, ya3, yb0, yb1, yb2, yb3);                         \
        LOADF8(kk * 64 + 96, ya0, ya1, ya2, ya3, yb0, yb1, yb2, yb3);           \
    }                                                                           \
    MFMA16(xa0, xa1, xa2, xa3, xb0, xb1, xb2, xb3);                             \
    MFMA16(ya0, ya1, ya2, ya3, yb0, yb1, yb2, yb3);                             \
    const int rbase = (lane >> 4) * 4;                                          \
    const int cbase = lane & 15;                                                \
    _Pragma("unroll")                                                           \
    for (int fi = 0; fi < 4; ++fi) {                                            \
        const int rm = m0 + wm * 64 + fi * 16 + rbase;                          \
        _Pragma("unroll")                                                       \
        for (int fj = 0; fj < 4; ++fj) {                                        \
            const int cn = n0 + wn * 64 + fj * 16 + cbase;                      \
            const float bv = bias[cn];                                          \
            _Pragma("unroll")                                                   \
            for (int r = 0; r < 4; ++r) {                                       \
                const int m = rm + r;                                           \
                const float val = acc[fi][fj][r] + bv;                          \
                EPILOGUE                                                        \
            }                                                                   \
        }                                                                       \
    }

// QKV GEMM: N=768; cols 0-255 -> qf fp32 (scaled); 256-511 -> kp; 512-767 -> vp
__global__ __launch_bounds__(256) void gemm_qkv(
    const __hip_bfloat16* __restrict__ A,
    const __hip_bfloat16* __restrict__ BT,
    const float* __restrict__ bias,
    float* __restrict__ qf,
    __hip_bfloat16* __restrict__ kp,
    __hip_bfloat16* __restrict__ vp,
    float qscale)
{
    GEMM_DIRECT_BODY({
        const int sel = cn >> 8;                       // 0=q,1=k,2=v (uniform/block)
        if (sel == 0) {
            qf[(size_t)m * 256 + cn] = val * qscale;
        } else {
            const int c  = cn & 255;
            const int b  = m / 3136;
            const int r2 = m % 3136;
            const int yy = r2 / 56;
            const int xx = r2 % 56;
            __hip_bfloat16* dst = (sel == 1) ? kp : vp;
            dst[(((size_t)(b * 64 + yy + 3)) * 64 + (xx + 3)) * 256 + c] =
                __float2bfloat16(val);
        }
    })
}

// proj GEMM: C fp32 [M][256] = A bf16 @ BT bf16 + bias
__global__ __launch_bounds__(256) void gemm_proj(
    const __hip_bfloat16* __restrict__ A,
    const __hip_bfloat16* __restrict__ BT,
    const float* __restrict__ bias,
    float* __restrict__ C)
{
    GEMM_DIRECT_BODY({
        C[(size_t)m * 256 + cn] = val;
    })
}

// ================= neighborhood attention, single-pass online softmax =======
// ONE WAVE per block (64 thr) = 4 tokens x 8 heads x 2 half-heads; grid 3136.
// Staging registers are EXPLICIT SCALARS expanded by macro: R10's uint4 g[5]
// arrays captured by-pointer in lambdas defeated SROA -> the arrays lived in
// scratch (VGPR=68 but WRITE_SIZE=113 MB of spill evictions; fixing this in
// R11 removed attn from the top-5). Named scalars + rolled ky loop (#pragma
// unroll 1; full unroll hoists ~280 VGPRs of loads, measured R8/R9 ->
// 256-VGPR spill) keep per-iteration liveness ~100 VGPRs.
// NEVER set the launch_bounds min-waves arg here (R6: cap 84 -> 1.4 GB spill;
// R7: cap 128 -> 0.8 GB spill).
// XCD swizzle: blockIdx round-robins XCDs, so seg = (bid&7)*392 + (bid>>3)
// gives each XCD 392 contiguous segments (~2.2 MB k/v working set < 4 MB L2):
// measured FETCH 126 -> 26.6 MB (R9 -> R10).
// Per ky: stage k-row AND v-row (10 cols x 256 ch bf16) into separate LDS
// buffers, 528 B col stride (132 words == 4 mod 32 -> measured 0 conflicts
// R6-R10); v-row loads in flight during QK, next k-row during the PV update.
// Single-buffered: same-wave DS ops are in-order. Zero-padded planes =>
// branch-free; OOB gives logit = rpb and v = 0 (reference zero-pad softmax).
__global__ __launch_bounds__(64) void na2d_attn9(
    const float* __restrict__ qf,
    const __hip_bfloat16* __restrict__ kp,
    const __hip_bfloat16* __restrict__ vp,
    const float* __restrict__ rpb,
    __hip_bfloat16* __restrict__ out)
{
    const int lane = threadIdx.x;       // 0..63
    const int half = lane & 1;          // 16-ch half of a head
    const int h    = (lane >> 1) & 7;   // head
    const int tl   = (lane >> 4) & 3;   // token within 4-token segment

    const int bid = blockIdx.x;         // 0..3135
    const int seg = (bid & 7) * 392 + (bid >> 3);   // XCD-contiguous remap
    const int row = seg / 14;           // b*56 + y
    const int x0  = (seg % 14) * 4;     // 0..52
    const int b   = row / 56;
    const int y   = row % 56;
    const int t   = row * 56 + x0 + tl;
    const int prow0 = b * 64 + y;       // padded plane row for ky=0

    __shared__ __hip_bfloat16 kbuf[10 * 264];   // 5.28 KB, col stride 528 B
    __shared__ __hip_bfloat16 vbuf[10 * 264];   // 5.28 KB
    __shared__ float srpb[8 * 49];

    for (int i = lane; i < 8 * 49; i += 64) srpb[i] = rpb[i];
    __syncthreads();                    // single-wave barrier: cheap

    // q: 16 fp32 channels (4 tokens' 256 ch are contiguous across the wave)
    float q[16];
    {
        const float4* qp = (const float4*)(qf + (size_t)t * 256 + h * 32 + half * 16);
        #pragma unroll
        for (int i = 0; i < 4; ++i) {
            const float4 v4 = qp[i];
            q[4 * i + 0] = v4.x; q[4 * i + 1] = v4.y;
            q[4 * i + 2] = v4.z; q[4 * i + 3] = v4.w;
        }
    }

    // LDS write offsets: unit=lane+i*64 -> col=2i+(lane>>5), j=lane&31
    // off_i = col*528 + j*16 = wroff + i*1056
    const int wroff = (lane >> 5) * 528 + (lane & 31) * 16;
    // LDS read base for this (tl,h,half); col offsets advance by 528/kx
    const int rdoff = tl * 528 + h * 64 + half * 32;

// load one padded row segment (10 cols x 256 ch bf16 = 5 KB) into 5 scalars
#define GLOAD(plane, ky, d0, d1, d2, d3, d4)                                    \
    do {                                                                        \
        const char* rb_ = (const char*)((plane) +                               \
            ((size_t)(prow0 + (ky)) * 64 + x0) * 256 + lane * 8);               \
        d0 = *(const uint4*)(rb_);                                              \
        d1 = *(const uint4*)(rb_ + 1024);                                       \
        d2 = *(const uint4*)(rb_ + 2048);                                       \
        d3 = *(const uint4*)(rb_ + 3072);                                       \
        d4 = *(const uint4*)(rb_ + 4096);                                       \
    } while (0)

#define LWRITE(buf, s0, s1, s2, s3, s4)                                         \
    do {                                                                        \
        char* wb_ = (char*)(buf) + wroff;                                       \
        *(uint4*)(wb_)        = s0;                                             \
        *(uint4*)(wb_ + 1056) = s1;                                             \
        *(uint4*)(wb_ + 2112) = s2;                                             \
        *(uint4*)(wb_ + 3168) = s3;                                             \
        *(uint4*)(wb_ + 4224) = s4;                                             \
    } while (0)

    const float* rp = &srpb[h * 49];
    float m = -1e30f, l = 0.f;
    float o[16] = {};

    uint4 k0, k1, k2, k3, k4, v0, v1, v2, v3, v4;
    GLOAD(kp, 0, k0, k1, k2, k3, k4);

    #pragma unroll 1
    for (int ky = 0; ky < 7; ++ky) {
        LWRITE(kbuf, k0, k1, k2, k3, k4);       // waits vmcnt for k row
        GLOAD(vp, ky, v0, v1, v2, v3, v4);      // v row in flight during QK
        // ---- 7 row logits from kbuf ----
        float lg[7];
        #pragma unroll
        for (int kx = 0; kx < 7; ++kx) {
            const uint4* p = (const uint4*)((const char*)kbuf + rdoff + kx * 528);
            float s = 0.f;
            #pragma unroll
            for (int qd = 0; qd < 2; ++qd) {
                const uint4 wv = p[qd];
                const int o8 = qd * 8;
                s += q[o8 + 0] * bflo(wv.x) + q[o8 + 1] * bfhi(wv.x)
                   + q[o8 + 2] * bflo(wv.y) + q[o8 + 3] * bfhi(wv.y)
                   + q[o8 + 4] * bflo(wv.z) + q[o8 + 5] * bfhi(wv.z)
                   + q[o8 + 6] * bflo(wv.w) + q[o8 + 7] * bfhi(wv.w);
            }
            lg[kx] = s;
        }
        LWRITE(vbuf, v0, v1, v2, v3, v4);       // waits vmcnt for v row
        if (ky < 6) GLOAD(kp, ky + 1, k0, k1, k2, k3, k4);  // next k in flight
        // ---- merge half-head partials + rpb ----
        #pragma unroll
        for (int kx = 0; kx < 7; ++kx) {
            lg[kx] += __shfl_xor(lg[kx], 1, 64);
            lg[kx] += rp[ky * 7 + kx];
        }
        // ---- online softmax update ----
        float rmax = lg[0];
        #pragma unroll
        for (int kx = 1; kx < 7; ++kx) rmax = fmaxf(rmax, lg[kx]);
        const float mnew  = fmaxf(m, rmax);
        const float alpha = __expf(m - mnew);   // ky=0: exp(-inf)=0
        m = mnew;
        l *= alpha;
        #pragma unroll
        for (int i = 0; i < 16; ++i) o[i] *= alpha;
        #pragma unroll
        for (int kx = 0; kx < 7; ++kx) {
            const float pr = __expf(lg[kx] - mnew);
            l += pr;
            const uint4* p = (const uint4*)((const char*)vbuf + rdoff + kx * 528);
            #pragma unroll
            for (int qd = 0; qd < 2; ++qd) {
                const uint4 wv = p[qd];
                const int o8 = qd * 8;
                o[o8 + 0] += pr * bflo(wv.x); o[o8 + 1] += pr * bfhi(wv.x);
                o[o8 + 2] += pr * bflo(wv.y); o[o8 + 3] += pr * bfhi(wv.y);
                o[o8 + 4] += pr * bflo(wv.z); o[o8 + 5] += pr * bfhi(wv.z);
                o[o8 + 6] += pr * bflo(wv.w); o[o8 + 7] += pr * bfhi(wv.w);
            }
        }
    }
#undef GLOAD
#undef LWRITE

    // ---- store bf16 (feeds proj GEMM) ----
    const float inv = 1.f / l;
    union { uint4 u[2]; __hip_bfloat16 hh[16]; } ob;
    #pragma unroll
    for (int i = 0; i < 16; ++i) ob.hh[i] = __float2bfloat16(o[i] * inv);
    uint4* op = (uint4*)(out + (size_t)t * 256 + h * 32 + half * 16);
    op[0] = ob.u[0];
    op[1] = ob.u[1];
}

extern "C" void kernel_launch(void* const* d_in, const int* in_sizes, int n_in,
                              void* d_out, int out_size, void* d_ws, size_t ws_size,
                              hipStream_t stream)
{
    const float* x      = (const float*)d_in[0];   // (4,56,56,256)
    const float* w_qkv  = (const float*)d_in[1];   // (256,768)
    const float* b_qkv  = (const float*)d_in[2];   // (768,)
    const float* rpb    = (const float*)d_in[3];   // (8,49)
    const float* w_proj = (const float*)d_in[4];   // (256,256)
    const float* b_proj = (const float*)d_in[5];   // (256,)
    float* out = (float*)d_out;                    // (4,56,56,256) fp32

    const int M = 12544;

    char* wsp = (char*)d_ws;
    float* qf = (float*)wsp;                      wsp += (size_t)M * 256 * 4;   // 12.85 MB
    __hip_bfloat16* kp    = (__hip_bfloat16*)wsp; wsp += (size_t)4 * 64 * 64 * 256 * 2; // 8.39 MB
    __hip_bfloat16* vp    = (__hip_bfloat16*)wsp; wsp += (size_t)4 * 64 * 64 * 256 * 2; // 8.39 MB
    __hip_bfloat16* xb    = (__hip_bfloat16*)wsp; wsp += (size_t)M * 256 * 2;
    __hip_bfloat16* attnb = (__hip_bfloat16*)wsp; wsp += (size_t)M * 256 * 2;
    __hip_bfloat16* wqkvT = (__hip_bfloat16*)wsp; wsp += (size_t)768 * 256 * 2;
    __hip_bfloat16* wprojT= (__hip_bfloat16*)wsp; wsp += (size_t)256 * 256 * 2;

    const float scale = 0.17677669529663689f;  // 32^-0.5

    // fused prep: x->bf16, both weight transposes, pad-border zero of kp/vp
    prep<<<5120, 256, 0, stream>>>(x, xb, w_qkv, wqkvT, w_proj, wprojT, kp, vp);

    // qkv = xb @ wqkvT^T + b_qkv; q fp32 scaled -> qf; k/v bf16 -> padded planes
    gemm_qkv<<<dim3(6, 98), 256, 0, stream>>>(xb, wqkvT, b_qkv, qf, kp, vp, scale);

    // attention: 3136 blocks x 64 threads, single-pass online softmax, rolled ky
    na2d_attn9<<<3136, 64, 0, stream>>>(qf, kp, vp, rpb, attnb);

    // out = attnb @ wprojT^T + b_proj
    gemm_proj<<<dim3(2, 98), 256, 0, stream>>>(attnb, wprojT, b_proj, out);
}

// Round 13
// 139.757 us; speedup vs baseline: 1.0809x; 1.0809x over previous
//
#include <hip/hip_runtime.h>
#include <hip/hip_bf16.h>

// Shapes (fixed): B=4, H=56, W=56, C=256, NH=8, HD=32, KS=7, PAD=3
// tokens M = 4*56*56 = 12544. Padded k/v planes: [4][64][64][256] bf16,
// interior token (y,x) at plane row y+3, col x+3; border zeroed by prep.
//
// R12 lesson: LDS-free direct-fragment GEMM (per-wave global_load_dwordx4 of
// fragments, no barriers) REGRESSED 139.5 -> 151 us vs this staged version:
// duplicate fetches + thin per-wave VMEM dependency chain at ~2 blocks/CU
// can't cover L2 latency; global_load_lds staging decouples the queue.

using frag_ab = __attribute__((ext_vector_type(8))) short;  // 8 bf16 (4 VGPRs)
using f32x4   = __attribute__((ext_vector_type(4))) float;  // 4 fp32 acc

typedef const __attribute__((address_space(1))) unsigned int* gas_u32;
typedef __attribute__((address_space(3))) unsigned int*       las_u32;

__device__ __forceinline__ void gl_lds16(const void* g, void* l) {
    // async global->LDS DMA, 16 B/lane; LDS dst = wave-uniform base + lane*16
    __builtin_amdgcn_global_load_lds((gas_u32)g, (las_u32)l, 16, 0, 0);
}

__device__ __forceinline__ float bflo(unsigned int u) { return __uint_as_float(u << 16); }
__device__ __forceinline__ float bfhi(unsigned int u) { return __uint_as_float(u & 0xffff0000u); }

// ================= fused prep =================
// blocks [0,3136):    x fp32 -> xb bf16 (float4/thread)
// blocks [3136,3904): w_qkv [256][768] -> wqkvT [768][256] bf16
// blocks [3904,4160): w_proj [256][256] -> wprojT [256][256] bf16
// blocks [4160,5120): zero the 960 border cols of each padded plane
__global__ __launch_bounds__(256) void prep(
    const float* __restrict__ x,      __hip_bfloat16* __restrict__ xb,
    const float* __restrict__ w_qkv,  __hip_bfloat16* __restrict__ wqkvT,
    const float* __restrict__ w_proj, __hip_bfloat16* __restrict__ wprojT,
    __hip_bfloat16* __restrict__ kp,  __hip_bfloat16* __restrict__ vp)
{
    const int bid = blockIdx.x;
    const int tid = threadIdx.x;
    if (bid < 3136) {
        const int i = bid * 256 + tid;            // over M*256/4 = 802816
        const float4 v = ((const float4*)x)[i];
        union { ushort4 u; __hip_bfloat16 h[4]; } o;
        o.h[0] = __float2bfloat16(v.x); o.h[1] = __float2bfloat16(v.y);
        o.h[2] = __float2bfloat16(v.z); o.h[3] = __float2bfloat16(v.w);
        ((ushort4*)xb)[i] = o.u;
    } else if (bid < 3904) {
        const int idx = (bid - 3136) * 256 + tid; // over 768*256
        const int k = idx & 255, n = idx >> 8;
        wqkvT[idx] = __float2bfloat16(w_qkv[k * 768 + n]);
    } else if (bid < 4160) {
        const int idx = (bid - 3904) * 256 + tid; // over 256*256
        const int k = idx & 255, n = idx >> 8;
        wprojT[idx] = __float2bfloat16(w_proj[k * 256 + n]);
    } else {
        const int u    = (bid - 4160) * 256 + tid;   // over 8*30720
        const int ip   = u / 30720;                  // img*2 + plane
        const int rem  = u - ip * 30720;
        const int cloc = rem >> 5;                   // 0..959 border cells
        const int q16  = rem & 31;                   // 16B chunk of 256 ch
        const int img  = ip >> 1;
        __hip_bfloat16* base = (ip & 1) ? vp : kp;
        int prow, pcol;
        if (cloc < 512) {                            // full pad rows 0-2,59-63
            const int r8 = cloc >> 6;
            prow = (r8 < 3) ? r8 : r8 + 56;
            pcol = cloc & 63;
        } else {                                     // side pads of rows 3..58
            const int c2 = cloc - 512;
            prow = 3 + (c2 >> 3);
            const int cc = c2 & 7;
            pcol = (cc < 3) ? cc : cc + 56;
        }
        *(uint4*)(base + (((size_t)(img * 64 + prow)) * 64 + pcol) * 256 + q16 * 8) =
            make_uint4(0u, 0u, 0u, 0u);
    }
}

// ================= 128x128 bf16 MFMA GEMM cores (staged, R11-measured-best) ==
// 256 thr = 4 waves; wave w owns quadrant (w>>1, w&1) as 4x4 16x16x32 frags.
// Staging in fragment order via global_load_lds: wave w DMAs A row-blocks
// 2w,2w+1 and B row-blocks 2w,2w+1 (block = 16 rows x 32 k = 64 lanes x 16 B).
#define GEMM128_BODY(EPILOGUE)                                                  \
    constexpr int K = 256;                                                      \
    __shared__ frag_ab As[8][64];   /* 8 KB */                                  \
    __shared__ frag_ab Bs[8][64];   /* 8 KB */                                  \
    const int tid  = threadIdx.x;                                               \
    const int lane = tid & 63;                                                  \
    const int w    = tid >> 6;                                                  \
    const int wm   = w >> 1, wn = w & 1;                                        \
    const int m0 = blockIdx.y * 128;                                            \
    const int n0 = blockIdx.x * 128;                                            \
    const int lrow = lane & 15;                                                 \
    const int lk   = (lane >> 4) * 8;                                           \
    const __hip_bfloat16* gA0 = A  + (size_t)(m0 + (2*w+0)*16 + lrow) * K + lk; \
    const __hip_bfloat16* gA1 = A  + (size_t)(m0 + (2*w+1)*16 + lrow) * K + lk; \
    const __hip_bfloat16* gB0 = BT + (size_t)(n0 + (2*w+0)*16 + lrow) * K + lk; \
    const __hip_bfloat16* gB1 = BT + (size_t)(n0 + (2*w+1)*16 + lrow) * K + lk; \
    f32x4 acc[4][4] = {};                                                       \
    for (int k0 = 0; k0 < K; k0 += 32) {                                        \
        gl_lds16(gA0 + k0, &As[2*w+0][0]);                                      \
        gl_lds16(gA1 + k0, &As[2*w+1][0]);                                      \
        gl_lds16(gB0 + k0, &Bs[2*w+0][0]);                                      \
        gl_lds16(gB1 + k0, &Bs[2*w+1][0]);                                      \
        __syncthreads();                                                        \
        frag_ab af[4], bf[4];                                                   \
        _Pragma("unroll")                                                       \
        for (int i = 0; i < 4; ++i) { af[i] = As[wm*4+i][lane]; bf[i] = Bs[wn*4+i][lane]; } \
        _Pragma("unroll")                                                       \
        for (int i = 0; i < 4; ++i)                                             \
            _Pragma("unroll")                                                   \
            for (int j = 0; j < 4; ++j)                                         \
                acc[i][j] = __builtin_amdgcn_mfma_f32_16x16x32_bf16(af[i], bf[j], acc[i][j], 0, 0, 0); \
        __syncthreads();                                                        \
    }                                                                           \
    const int rbase = (lane >> 4) * 4;                                          \
    const int cbase = lane & 15;                                                \
    _Pragma("unroll")                                                           \
    for (int fi = 0; fi < 4; ++fi) {                                            \
        const int rm = m0 + wm * 64 + fi * 16 + rbase;                          \
        _Pragma("unroll")                                                       \
        for (int fj = 0; fj < 4; ++fj) {                                        \
            const int cn = n0 + wn * 64 + fj * 16 + cbase;                      \
            const float bv = bias[cn];                                          \
            _Pragma("unroll")                                                   \
            for (int r = 0; r < 4; ++r) {                                       \
                const int m = rm + r;                                           \
                const float val = acc[fi][fj][r] + bv;                          \
                EPILOGUE                                                        \
            }                                                                   \
        }                                                                       \
    }

// QKV GEMM: N=768; cols 0-255 -> qf fp32 (scaled); 256-511 -> kp; 512-767 -> vp
__global__ __launch_bounds__(256) void gemm_qkv(
    const __hip_bfloat16* __restrict__ A,
    const __hip_bfloat16* __restrict__ BT,
    const float* __restrict__ bias,
    float* __restrict__ qf,
    __hip_bfloat16* __restrict__ kp,
    __hip_bfloat16* __restrict__ vp,
    float qscale)
{
    GEMM128_BODY({
        const int sel = cn >> 8;                       // 0=q,1=k,2=v (uniform/block)
        if (sel == 0) {
            qf[(size_t)m * 256 + cn] = val * qscale;
        } else {
            const int c  = cn & 255;
            const int b  = m / 3136;
            const int r2 = m % 3136;
            const int yy = r2 / 56;
            const int xx = r2 % 56;
            __hip_bfloat16* dst = (sel == 1) ? kp : vp;
            dst[(((size_t)(b * 64 + yy + 3)) * 64 + (xx + 3)) * 256 + c] =
                __float2bfloat16(val);
        }
    })
}

// proj GEMM: C fp32 [M][256] = A bf16 @ BT bf16 + bias
__global__ __launch_bounds__(256) void gemm_proj(
    const __hip_bfloat16* __restrict__ A,
    const __hip_bfloat16* __restrict__ BT,
    const float* __restrict__ bias,
    float* __restrict__ C)
{
    GEMM128_BODY({
        C[(size_t)m * 256 + cn] = val;
    })
}

// ================= neighborhood attention, single-pass online softmax =======
// ONE WAVE per block (64 thr) = 4 tokens x 8 heads x 2 half-heads; grid 3136.
// Staging registers are EXPLICIT SCALARS expanded by macro: R10's uint4 g[5]
// arrays captured by-pointer in lambdas defeated SROA -> the arrays lived in
// scratch (VGPR=68 but WRITE_SIZE=113 MB of spill evictions; fixing this in
// R11 removed attn from the top-5). Named scalars + rolled ky loop (#pragma
// unroll 1; full unroll hoists ~280 VGPRs of loads, measured R8/R9 ->
// 256-VGPR spill) keep per-iteration liveness ~100 VGPRs.
// NEVER set the launch_bounds min-waves arg here (R6: cap 84 -> 1.4 GB spill;
// R7: cap 128 -> 0.8 GB spill).
// XCD swizzle: blockIdx round-robins XCDs, so seg = (bid&7)*392 + (bid>>3)
// gives each XCD 392 contiguous segments (~2.2 MB k/v working set < 4 MB L2):
// measured FETCH 126 -> 26.6 MB (R9 -> R10).
// Per ky: stage k-row AND v-row (10 cols x 256 ch bf16) into separate LDS
// buffers, 528 B col stride (132 words == 4 mod 32 -> measured 0 conflicts
// R6-R10); v-row loads in flight during QK, next k-row during the PV update.
// Single-buffered: same-wave DS ops are in-order. Zero-padded planes =>
// branch-free; OOB gives logit = rpb and v = 0 (reference zero-pad softmax).
__global__ __launch_bounds__(64) void na2d_attn9(
    const float* __restrict__ qf,
    const __hip_bfloat16* __restrict__ kp,
    const __hip_bfloat16* __restrict__ vp,
    const float* __restrict__ rpb,
    __hip_bfloat16* __restrict__ out)
{
    const int lane = threadIdx.x;       // 0..63
    const int half = lane & 1;          // 16-ch half of a head
    const int h    = (lane >> 1) & 7;   // head
    const int tl   = (lane >> 4) & 3;   // token within 4-token segment

    const int bid = blockIdx.x;         // 0..3135
    const int seg = (bid & 7) * 392 + (bid >> 3);   // XCD-contiguous remap
    const int row = seg / 14;           // b*56 + y
    const int x0  = (seg % 14) * 4;     // 0..52
    const int b   = row / 56;
    const int y   = row % 56;
    const int t   = row * 56 + x0 + tl;
    const int prow0 = b * 64 + y;       // padded plane row for ky=0

    __shared__ __hip_bfloat16 kbuf[10 * 264];   // 5.28 KB, col stride 528 B
    __shared__ __hip_bfloat16 vbuf[10 * 264];   // 5.28 KB
    __shared__ float srpb[8 * 49];

    for (int i = lane; i < 8 * 49; i += 64) srpb[i] = rpb[i];
    __syncthreads();                    // single-wave barrier: cheap

    // q: 16 fp32 channels (4 tokens' 256 ch are contiguous across the wave)
    float q[16];
    {
        const float4* qp = (const float4*)(qf + (size_t)t * 256 + h * 32 + half * 16);
        #pragma unroll
        for (int i = 0; i < 4; ++i) {
            const float4 v4 = qp[i];
            q[4 * i + 0] = v4.x; q[4 * i + 1] = v4.y;
            q[4 * i + 2] = v4.z; q[4 * i + 3] = v4.w;
        }
    }

    // LDS write offsets: unit=lane+i*64 -> col=2i+(lane>>5), j=lane&31
    // off_i = col*528 + j*16 = wroff + i*1056
    const int wroff = (lane >> 5) * 528 + (lane & 31) * 16;
    // LDS read base for this (tl,h,half); col offsets advance by 528/kx
    const int rdoff = tl * 528 + h * 64 + half * 32;

// load one padded row segment (10 cols x 256 ch bf16 = 5 KB) into 5 scalars
#define GLOAD(plane, ky, d0, d1, d2, d3, d4)                                    \
    do {                                                                        \
        const char* rb_ = (const char*)((plane) +                               \
            ((size_t)(prow0 + (ky)) * 64 + x0) * 256 + lane * 8);               \
        d0 = *(const uint4*)(rb_);                                              \
        d1 = *(const uint4*)(rb_ + 1024);                                       \
        d2 = *(const uint4*)(rb_ + 2048);                                       \
        d3 = *(const uint4*)(rb_ + 3072);                                       \
        d4 = *(const uint4*)(rb_ + 4096);                                       \
    } while (0)

#define LWRITE(buf, s0, s1, s2, s3, s4)                                         \
    do {                                                                        \
        char* wb_ = (char*)(buf) + wroff;                                       \
        *(uint4*)(wb_)        = s0;                                             \
        *(uint4*)(wb_ + 1056) = s1;                                             \
        *(uint4*)(wb_ + 2112) = s2;                                             \
        *(uint4*)(wb_ + 3168) = s3;                                             \
        *(uint4*)(wb_ + 4224) = s4;                                             \
    } while (0)

    const float* rp = &srpb[h * 49];
    float m = -1e30f, l = 0.f;
    float o[16] = {};

    uint4 k0, k1, k2, k3, k4, v0, v1, v2, v3, v4;
    GLOAD(kp, 0, k0, k1, k2, k3, k4);

    #pragma unroll 1
    for (int ky = 0; ky < 7; ++ky) {
        LWRITE(kbuf, k0, k1, k2, k3, k4);       // waits vmcnt for k row
        GLOAD(vp, ky, v0, v1, v2, v3, v4);      // v row in flight during QK
        // ---- 7 row logits from kbuf ----
        float lg[7];
        #pragma unroll
        for (int kx = 0; kx < 7; ++kx) {
            const uint4* p = (const uint4*)((const char*)kbuf + rdoff + kx * 528);
            float s = 0.f;
            #pragma unroll
            for (int qd = 0; qd < 2; ++qd) {
                const uint4 wv = p[qd];
                const int o8 = qd * 8;
                s += q[o8 + 0] * bflo(wv.x) + q[o8 + 1] * bfhi(wv.x)
                   + q[o8 + 2] * bflo(wv.y) + q[o8 + 3] * bfhi(wv.y)
                   + q[o8 + 4] * bflo(wv.z) + q[o8 + 5] * bfhi(wv.z)
                   + q[o8 + 6] * bflo(wv.w) + q[o8 + 7] * bfhi(wv.w);
            }
            lg[kx] = s;
        }
        LWRITE(vbuf, v0, v1, v2, v3, v4);       // waits vmcnt for v row
        if (ky < 6) GLOAD(kp, ky + 1, k0, k1, k2, k3, k4);  // next k in flight
        // ---- merge half-head partials + rpb ----
        #pragma unroll
        for (int kx = 0; kx < 7; ++kx) {
            lg[kx] += __shfl_xor(lg[kx], 1, 64);
            lg[kx] += rp[ky * 7 + kx];
        }
        // ---- online softmax update ----
        float rmax = lg[0];
        #pragma unroll
        for (int kx = 1; kx < 7; ++kx) rmax = fmaxf(rmax, lg[kx]);
        const float mnew  = fmaxf(m, rmax);
        const float alpha = __expf(m - mnew);   // ky=0: exp(-inf)=0
        m = mnew;
        l *= alpha;
        #pragma unroll
        for (int i = 0; i < 16; ++i) o[i] *= alpha;
        #pragma unroll
        for (int kx = 0; kx < 7; ++kx) {
            const float pr = __expf(lg[kx] - mnew);
            l += pr;
            const uint4* p = (const uint4*)((const char*)vbuf + rdoff + kx * 528);
            #pragma unroll
            for (int qd = 0; qd < 2; ++qd) {
                const uint4 wv = p[qd];
                const int o8 = qd * 8;
                o[o8 + 0] += pr * bflo(wv.x); o[o8 + 1] += pr * bfhi(wv.x);
                o[o8 + 2] += pr * bflo(wv.y); o[o8 + 3] += pr * bfhi(wv.y);
                o[o8 + 4] += pr * bflo(wv.z); o[o8 + 5] += pr * bfhi(wv.z);
                o[o8 + 6] += pr * bflo(wv.w); o[o8 + 7] += pr * bfhi(wv.w);
            }
        }
    }
#undef GLOAD
#undef LWRITE

    // ---- store bf16 (feeds proj GEMM) ----
    const float inv = 1.f / l;
    union { uint4 u[2]; __hip_bfloat16 hh[16]; } ob;
    #pragma unroll
    for (int i = 0; i < 16; ++i) ob.hh[i] = __float2bfloat16(o[i] * inv);
    uint4* op = (uint4*)(out + (size_t)t * 256 + h * 32 + half * 16);
    op[0] = ob.u[0];
    op[1] = ob.u[1];
}

extern "C" void kernel_launch(void* const* d_in, const int* in_sizes, int n_in,
                              void* d_out, int out_size, void* d_ws, size_t ws_size,
                              hipStream_t stream)
{
    const float* x      = (const float*)d_in[0];   // (4,56,56,256)
    const float* w_qkv  = (const float*)d_in[1];   // (256,768)
    const float* b_qkv  = (const float*)d_in[2];   // (768,)
    const float* rpb    = (const float*)d_in[3];   // (8,49)
    const float* w_proj = (const float*)d_in[4];   // (256,256)
    const float* b_proj = (const float*)d_in[5];   // (256,)
    float* out = (float*)d_out;                    // (4,56,56,256) fp32

    const int M = 12544;

    char* wsp = (char*)d_ws;
    float* qf = (float*)wsp;                      wsp += (size_t)M * 256 * 4;   // 12.85 MB
    __hip_bfloat16* kp    = (__hip_bfloat16*)wsp; wsp += (size_t)4 * 64 * 64 * 256 * 2; // 8.39 MB
    __hip_bfloat16* vp    = (__hip_bfloat16*)wsp; wsp += (size_t)4 * 64 * 64 * 256 * 2; // 8.39 MB
    __hip_bfloat16* xb    = (__hip_bfloat16*)wsp; wsp += (size_t)M * 256 * 2;
    __hip_bfloat16* attnb = (__hip_bfloat16*)wsp; wsp += (size_t)M * 256 * 2;
    __hip_bfloat16* wqkvT = (__hip_bfloat16*)wsp; wsp += (size_t)768 * 256 * 2;
    __hip_bfloat16* wprojT= (__hip_bfloat16*)wsp; wsp += (size_t)256 * 256 * 2;

    const float scale = 0.17677669529663689f;  // 32^-0.5

    // fused prep: x->bf16, both weight transposes, pad-border zero of kp/vp
    prep<<<5120, 256, 0, stream>>>(x, xb, w_qkv, wqkvT, w_proj, wprojT, kp, vp);

    // qkv = xb @ wqkvT^T + b_qkv; q fp32 scaled -> qf; k/v bf16 -> padded planes
    gemm_qkv<<<dim3(6, 98), 256, 0, stream>>>(xb, wqkvT, b_qkv, qf, kp, vp, scale);

    // attention: 3136 blocks x 64 threads, single-pass online softmax, rolled ky
    na2d_attn9<<<3136, 64, 0, stream>>>(qf, kp, vp, rpb, attnb);

    // out = attnb @ wprojT^T + b_proj
    gemm_proj<<<dim3(2, 98), 256, 0, stream>>>(attnb, wprojT, b_proj, out);
}

// Round 14
// 138.660 us; speedup vs baseline: 1.0894x; 1.0079x over previous
//
#include <hip/hip_runtime.h>
#include <hip/hip_bf16.h>

// Shapes (fixed): B=4, H=56, W=56, C=256, NH=8, HD=32, KS=7, PAD=3
// tokens M = 4*56*56 = 12544. Padded k/v planes: [4][64][64][256] bf16,
// interior token (y,x) at plane row y+3, col x+3; border zeroed by prep.
//
// R12 lesson: LDS-free direct-fragment GEMM (per-wave global_load_dwordx4 of
// fragments, no barriers) REGRESSED 139.5 -> 151 us vs the staged version:
// duplicate fetches + thin per-wave VMEM dependency chain at ~2 blocks/CU
// can't cover L2 latency; global_load_lds staging decouples the queue.
// R14: proj re-tiled 128x128 -> 64x64 (196 -> 784 blocks): 196 blocks left
// 60 CUs idle and no block-overlap to hide the 8 barrier drains.

using frag_ab = __attribute__((ext_vector_type(8))) short;  // 8 bf16 (4 VGPRs)
using f32x4   = __attribute__((ext_vector_type(4))) float;  // 4 fp32 acc

typedef const __attribute__((address_space(1))) unsigned int* gas_u32;
typedef __attribute__((address_space(3))) unsigned int*       las_u32;

__device__ __forceinline__ void gl_lds16(const void* g, void* l) {
    // async global->LDS DMA, 16 B/lane; LDS dst = wave-uniform base + lane*16
    __builtin_amdgcn_global_load_lds((gas_u32)g, (las_u32)l, 16, 0, 0);
}

__device__ __forceinline__ float bflo(unsigned int u) { return __uint_as_float(u << 16); }
__device__ __forceinline__ float bfhi(unsigned int u) { return __uint_as_float(u & 0xffff0000u); }

// ================= fused prep =================
// blocks [0,3136):    x fp32 -> xb bf16 (float4/thread)
// blocks [3136,3904): w_qkv [256][768] -> wqkvT [768][256] bf16
// blocks [3904,4160): w_proj [256][256] -> wprojT [256][256] bf16
// blocks [4160,5120): zero the 960 border cols of each padded plane
__global__ __launch_bounds__(256) void prep(
    const float* __restrict__ x,      __hip_bfloat16* __restrict__ xb,
    const float* __restrict__ w_qkv,  __hip_bfloat16* __restrict__ wqkvT,
    const float* __restrict__ w_proj, __hip_bfloat16* __restrict__ wprojT,
    __hip_bfloat16* __restrict__ kp,  __hip_bfloat16* __restrict__ vp)
{
    const int bid = blockIdx.x;
    const int tid = threadIdx.x;
    if (bid < 3136) {
        const int i = bid * 256 + tid;            // over M*256/4 = 802816
        const float4 v = ((const float4*)x)[i];
        union { ushort4 u; __hip_bfloat16 h[4]; } o;
        o.h[0] = __float2bfloat16(v.x); o.h[1] = __float2bfloat16(v.y);
        o.h[2] = __float2bfloat16(v.z); o.h[3] = __float2bfloat16(v.w);
        ((ushort4*)xb)[i] = o.u;
    } else if (bid < 3904) {
        const int idx = (bid - 3136) * 256 + tid; // over 768*256
        const int k = idx & 255, n = idx >> 8;
        wqkvT[idx] = __float2bfloat16(w_qkv[k * 768 + n]);
    } else if (bid < 4160) {
        const int idx = (bid - 3904) * 256 + tid; // over 256*256
        const int k = idx & 255, n = idx >> 8;
        wprojT[idx] = __float2bfloat16(w_proj[k * 256 + n]);
    } else {
        const int u    = (bid - 4160) * 256 + tid;   // over 8*30720
        const int ip   = u / 30720;                  // img*2 + plane
        const int rem  = u - ip * 30720;
        const int cloc = rem >> 5;                   // 0..959 border cells
        const int q16  = rem & 31;                   // 16B chunk of 256 ch
        const int img  = ip >> 1;
        __hip_bfloat16* base = (ip & 1) ? vp : kp;
        int prow, pcol;
        if (cloc < 512) {                            // full pad rows 0-2,59-63
            const int r8 = cloc >> 6;
            prow = (r8 < 3) ? r8 : r8 + 56;
            pcol = cloc & 63;
        } else {                                     // side pads of rows 3..58
            const int c2 = cloc - 512;
            prow = 3 + (c2 >> 3);
            const int cc = c2 & 7;
            pcol = (cc < 3) ? cc : cc + 56;
        }
        *(uint4*)(base + (((size_t)(img * 64 + prow)) * 64 + pcol) * 256 + q16 * 8) =
            make_uint4(0u, 0u, 0u, 0u);
    }
}

// ================= 128x128 bf16 MFMA GEMM core (staged, R11-measured-best) ==
// 256 thr = 4 waves; wave w owns quadrant (w>>1, w&1) as 4x4 16x16x32 frags.
// Staging in fragment order via global_load_lds: wave w DMAs A row-blocks
// 2w,2w+1 and B row-blocks 2w,2w+1 (block = 16 rows x 32 k = 64 lanes x 16 B).
#define GEMM128_BODY(EPILOGUE)                                                  \
    constexpr int K = 256;                                                      \
    __shared__ frag_ab As[8][64];   /* 8 KB */                                  \
    __shared__ frag_ab Bs[8][64];   /* 8 KB */                                  \
    const int tid  = threadIdx.x;                                               \
    const int lane = tid & 63;                                                  \
    const int w    = tid >> 6;                                                  \
    const int wm   = w >> 1, wn = w & 1;                                        \
    const int m0 = blockIdx.y * 128;                                            \
    const int n0 = blockIdx.x * 128;                                            \
    const int lrow = lane & 15;                                                 \
    const int lk   = (lane >> 4) * 8;                                           \
    const __hip_bfloat16* gA0 = A  + (size_t)(m0 + (2*w+0)*16 + lrow) * K + lk; \
    const __hip_bfloat16* gA1 = A  + (size_t)(m0 + (2*w+1)*16 + lrow) * K + lk; \
    const __hip_bfloat16* gB0 = BT + (size_t)(n0 + (2*w+0)*16 + lrow) * K + lk; \
    const __hip_bfloat16* gB1 = BT + (size_t)(n0 + (2*w+1)*16 + lrow) * K + lk; \
    f32x4 acc[4][4] = {};                                                       \
    for (int k0 = 0; k0 < K; k0 += 32) {                                        \
        gl_lds16(gA0 + k0, &As[2*w+0][0]);                                      \
        gl_lds16(gA1 + k0, &As[2*w+1][0]);                                      \
        gl_lds16(gB0 + k0, &Bs[2*w+0][0]);                                      \
        gl_lds16(gB1 + k0, &Bs[2*w+1][0]);                                      \
        __syncthreads();                                                        \
        frag_ab af[4], bf[4];                                                   \
        _Pragma("unroll")                                                       \
        for (int i = 0; i < 4; ++i) { af[i] = As[wm*4+i][lane]; bf[i] = Bs[wn*4+i][lane]; } \
        _Pragma("unroll")                                                       \
        for (int i = 0; i < 4; ++i)                                             \
            _Pragma("unroll")                                                   \
            for (int j = 0; j < 4; ++j)                                         \
                acc[i][j] = __builtin_amdgcn_mfma_f32_16x16x32_bf16(af[i], bf[j], acc[i][j], 0, 0, 0); \
        __syncthreads();                                                        \
    }                                                                           \
    const int rbase = (lane >> 4) * 4;                                          \
    const int cbase = lane & 15;                                                \
    _Pragma("unroll")                                                           \
    for (int fi = 0; fi < 4; ++fi) {                                            \
        const int rm = m0 + wm * 64 + fi * 16 + rbase;                          \
        _Pragma("unroll")                                                       \
        for (int fj = 0; fj < 4; ++fj) {                                        \
            const int cn = n0 + wn * 64 + fj * 16 + cbase;                      \
            const float bv = bias[cn];                                          \
            _Pragma("unroll")                                                   \
            for (int r = 0; r < 4; ++r) {                                       \
                const int m = rm + r;                                           \
                const float val = acc[fi][fj][r] + bv;                          \
                EPILOGUE                                                        \
            }                                                                   \
        }                                                                       \
    }

// QKV GEMM: N=768; cols 0-255 -> qf fp32 (scaled); 256-511 -> kp; 512-767 -> vp
__global__ __launch_bounds__(256) void gemm_qkv(
    const __hip_bfloat16* __restrict__ A,
    const __hip_bfloat16* __restrict__ BT,
    const float* __restrict__ bias,
    float* __restrict__ qf,
    __hip_bfloat16* __restrict__ kp,
    __hip_bfloat16* __restrict__ vp,
    float qscale)
{
    GEMM128_BODY({
        const int sel = cn >> 8;                       // 0=q,1=k,2=v (uniform/block)
        if (sel == 0) {
            qf[(size_t)m * 256 + cn] = val * qscale;
        } else {
            const int c  = cn & 255;
            const int b  = m / 3136;
            const int r2 = m % 3136;
            const int yy = r2 / 56;
            const int xx = r2 % 56;
            __hip_bfloat16* dst = (sel == 1) ? kp : vp;
            dst[(((size_t)(b * 64 + yy + 3)) * 64 + (xx + 3)) * 256 + c] =
                __float2bfloat16(val);
        }
    })
}

// ===== proj GEMM, 64x64 tile (R2-validated structure; grid 4x196 = 784 ======
// blocks ~= 3/CU vs 196 with the 128-tile: proj is occupancy-bound, not
// MFMA-bound). 4 waves; wave w owns 32x32 quadrant (w>>1, w&1) as 2x2 frags;
// wave w stages A row-block w and B row-block w in fragment order.
__global__ __launch_bounds__(256) void gemm_proj(
    const __hip_bfloat16* __restrict__ A,
    const __hip_bfloat16* __restrict__ BT,
    const float* __restrict__ bias,
    float* __restrict__ C)
{
    constexpr int K = 256;
    __shared__ frag_ab As[4][64];   // 4 KB
    __shared__ frag_ab Bs[4][64];   // 4 KB

    const int tid  = threadIdx.x;
    const int lane = tid & 63;
    const int w    = tid >> 6;
    const int wm   = w >> 1, wn = w & 1;
    const int m0 = blockIdx.y * 64;
    const int n0 = blockIdx.x * 64;

    const int lrow = lane & 15;
    const int lk   = (lane >> 4) * 8;
    const __hip_bfloat16* gA = A  + (size_t)(m0 + w * 16 + lrow) * K + lk;
    const __hip_bfloat16* gB = BT + (size_t)(n0 + w * 16 + lrow) * K + lk;

    f32x4 acc[2][2] = {};

    for (int k0 = 0; k0 < K; k0 += 32) {
        gl_lds16(gA + k0, &As[w][0]);
        gl_lds16(gB + k0, &Bs[w][0]);
        __syncthreads();
        const frag_ab a0 = As[2 * wm + 0][lane];
        const frag_ab a1 = As[2 * wm + 1][lane];
        const frag_ab b0 = Bs[2 * wn + 0][lane];
        const frag_ab b1 = Bs[2 * wn + 1][lane];
        acc[0][0] = __builtin_amdgcn_mfma_f32_16x16x32_bf16(a0, b0, acc[0][0], 0, 0, 0);
        acc[0][1] = __builtin_amdgcn_mfma_f32_16x16x32_bf16(a0, b1, acc[0][1], 0, 0, 0);
        acc[1][0] = __builtin_amdgcn_mfma_f32_16x16x32_bf16(a1, b0, acc[1][0], 0, 0, 0);
        acc[1][1] = __builtin_amdgcn_mfma_f32_16x16x32_bf16(a1, b1, acc[1][1], 0, 0, 0);
        __syncthreads();
    }

    const int rbase = (lane >> 4) * 4;
    const int cbase = lane & 15;
    #pragma unroll
    for (int fi = 0; fi < 2; ++fi) {
        const int rm = m0 + wm * 32 + fi * 16 + rbase;
        #pragma unroll
        for (int fj = 0; fj < 2; ++fj) {
            const int cn = n0 + wn * 32 + fj * 16 + cbase;
            const float bv = bias[cn];
            #pragma unroll
            for (int r = 0; r < 4; ++r)
                C[(size_t)(rm + r) * 256 + cn] = acc[fi][fj][r] + bv;
        }
    }
}

// ================= neighborhood attention, single-pass online softmax =======
// ONE WAVE per block (64 thr) = 4 tokens x 8 heads x 2 half-heads; grid 3136.
// Staging registers are EXPLICIT SCALARS expanded by macro: R10's uint4 g[5]
// arrays captured by-pointer in lambdas defeated SROA -> the arrays lived in
// scratch (VGPR=68 but WRITE_SIZE=113 MB of spill evictions; fixing this in
// R11 removed attn from the top-5). Named scalars + rolled ky loop (#pragma
// unroll 1; full unroll hoists ~280 VGPRs of loads, measured R8/R9 ->
// 256-VGPR spill) keep per-iteration liveness ~100 VGPRs.
// NEVER set the launch_bounds min-waves arg here (R6: cap 84 -> 1.4 GB spill;
// R7: cap 128 -> 0.8 GB spill).
// XCD swizzle: blockIdx round-robins XCDs, so seg = (bid&7)*392 + (bid>>3)
// gives each XCD 392 contiguous segments (~2.2 MB k/v working set < 4 MB L2):
// measured FETCH 126 -> 26.6 MB (R9 -> R10).
// Per ky: stage k-row AND v-row (10 cols x 256 ch bf16) into separate LDS
// buffers, 528 B col stride (132 words == 4 mod 32 -> measured 0 conflicts
// R6-R10); v-row loads in flight during QK, next k-row during the PV update.
// Single-buffered: same-wave DS ops are in-order. Zero-padded planes =>
// branch-free; OOB gives logit = rpb and v = 0 (reference zero-pad softmax).
__global__ __launch_bounds__(64) void na2d_attn9(
    const float* __restrict__ qf,
    const __hip_bfloat16* __restrict__ kp,
    const __hip_bfloat16* __restrict__ vp,
    const float* __restrict__ rpb,
    __hip_bfloat16* __restrict__ out)
{
    const int lane = threadIdx.x;       // 0..63
    const int half = lane & 1;          // 16-ch half of a head
    const int h    = (lane >> 1) & 7;   // head
    const int tl   = (lane >> 4) & 3;   // token within 4-token segment

    const int bid = blockIdx.x;         // 0..3135
    const int seg = (bid & 7) * 392 + (bid >> 3);   // XCD-contiguous remap
    const int row = seg / 14;           // b*56 + y
    const int x0  = (seg % 14) * 4;     // 0..52
    const int b   = row / 56;
    const int y   = row % 56;
    const int t   = row * 56 + x0 + tl;
    const int prow0 = b * 64 + y;       // padded plane row for ky=0

    __shared__ __hip_bfloat16 kbuf[10 * 264];   // 5.28 KB, col stride 528 B
    __shared__ __hip_bfloat16 vbuf[10 * 264];   // 5.28 KB
    __shared__ float srpb[8 * 49];

    for (int i = lane; i < 8 * 49; i += 64) srpb[i] = rpb[i];
    __syncthreads();                    // single-wave barrier: cheap

    // q: 16 fp32 channels (4 tokens' 256 ch are contiguous across the wave)
    float q[16];
    {
        const float4* qp = (const float4*)(qf + (size_t)t * 256 + h * 32 + half * 16);
        #pragma unroll
        for (int i = 0; i < 4; ++i) {
            const float4 v4 = qp[i];
            q[4 * i + 0] = v4.x; q[4 * i + 1] = v4.y;
            q[4 * i + 2] = v4.z; q[4 * i + 3] = v4.w;
        }
    }

    // LDS write offsets: unit=lane+i*64 -> col=2i+(lane>>5), j=lane&31
    // off_i = col*528 + j*16 = wroff + i*1056
    const int wroff = (lane >> 5) * 528 + (lane & 31) * 16;
    // LDS read base for this (tl,h,half); col offsets advance by 528/kx
    const int rdoff = tl * 528 + h * 64 + half * 32;

// load one padded row segment (10 cols x 256 ch bf16 = 5 KB) into 5 scalars
#define GLOAD(plane, ky, d0, d1, d2, d3, d4)                                    \
    do {                                                                        \
        const char* rb_ = (const char*)((plane) +                               \
            ((size_t)(prow0 + (ky)) * 64 + x0) * 256 + lane * 8);               \
        d0 = *(const uint4*)(rb_);                                              \
        d1 = *(const uint4*)(rb_ + 1024);                                       \
        d2 = *(const uint4*)(rb_ + 2048);                                       \
        d3 = *(const uint4*)(rb_ + 3072);                                       \
        d4 = *(const uint4*)(rb_ + 4096);                                       \
    } while (0)

#define LWRITE(buf, s0, s1, s2, s3, s4)                                         \
    do {                                                                        \
        char* wb_ = (char*)(buf) + wroff;                                       \
        *(uint4*)(wb_)        = s0;                                             \
        *(uint4*)(wb_ + 1056) = s1;                                             \
        *(uint4*)(wb_ + 2112) = s2;                                             \
        *(uint4*)(wb_ + 3168) = s3;                                             \
        *(uint4*)(wb_ + 4224) = s4;                                             \
    } while (0)

    const float* rp = &srpb[h * 49];
    float m = -1e30f, l = 0.f;
    float o[16] = {};

    uint4 k0, k1, k2, k3, k4, v0, v1, v2, v3, v4;
    GLOAD(kp, 0, k0, k1, k2, k3, k4);

    #pragma unroll 1
    for (int ky = 0; ky < 7; ++ky) {
        LWRITE(kbuf, k0, k1, k2, k3, k4);       // waits vmcnt for k row
        GLOAD(vp, ky, v0, v1, v2, v3, v4);      // v row in flight during QK
        // ---- 7 row logits from kbuf ----
        float lg[7];
        #pragma unroll
        for (int kx = 0; kx < 7; ++kx) {
            const uint4* p = (const uint4*)((const char*)kbuf + rdoff + kx * 528);
            float s = 0.f;
            #pragma unroll
            for (int qd = 0; qd < 2; ++qd) {
                const uint4 wv = p[qd];
                const int o8 = qd * 8;
                s += q[o8 + 0] * bflo(wv.x) + q[o8 + 1] * bfhi(wv.x)
                   + q[o8 + 2] * bflo(wv.y) + q[o8 + 3] * bfhi(wv.y)
                   + q[o8 + 4] * bflo(wv.z) + q[o8 + 5] * bfhi(wv.z)
                   + q[o8 + 6] * bflo(wv.w) + q[o8 + 7] * bfhi(wv.w);
            }
            lg[kx] = s;
        }
        LWRITE(vbuf, v0, v1, v2, v3, v4);       // waits vmcnt for v row
        if (ky < 6) GLOAD(kp, ky + 1, k0, k1, k2, k3, k4);  // next k in flight
        // ---- merge half-head partials + rpb ----
        #pragma unroll
        for (int kx = 0; kx < 7; ++kx) {
            lg[kx] += __shfl_xor(lg[kx], 1, 64);
            lg[kx] += rp[ky * 7 + kx];
        }
        // ---- online softmax update ----
        float rmax = lg[0];
        #pragma unroll
        for (int kx = 1; kx < 7; ++kx) rmax = fmaxf(rmax, lg[kx]);
        const float mnew  = fmaxf(m, rmax);
        const float alpha = __expf(m - mnew);   // ky=0: exp(-inf)=0
        m = mnew;
        l *= alpha;
        #pragma unroll
        for (int i = 0; i < 16; ++i) o[i] *= alpha;
        #pragma unroll
        for (int kx = 0; kx < 7; ++kx) {
            const float pr = __expf(lg[kx] - mnew);
            l += pr;
            const uint4* p = (const uint4*)((const char*)vbuf + rdoff + kx * 528);
            #pragma unroll
            for (int qd = 0; qd < 2; ++qd) {
                const uint4 wv = p[qd];
                const int o8 = qd * 8;
                o[o8 + 0] += pr * bflo(wv.x); o[o8 + 1] += pr * bfhi(wv.x);
                o[o8 + 2] += pr * bflo(wv.y); o[o8 + 3] += pr * bfhi(wv.y);
                o[o8 + 4] += pr * bflo(wv.z); o[o8 + 5] += pr * bfhi(wv.z);
                o[o8 + 6] += pr * bflo(wv.w); o[o8 + 7] += pr * bfhi(wv.w);
            }
        }
    }
#undef GLOAD
#undef LWRITE

    // ---- store bf16 (feeds proj GEMM) ----
    const float inv = 1.f / l;
    union { uint4 u[2]; __hip_bfloat16 hh[16]; } ob;
    #pragma unroll
    for (int i = 0; i < 16; ++i) ob.hh[i] = __float2bfloat16(o[i] * inv);
    uint4* op = (uint4*)(out + (size_t)t * 256 + h * 32 + half * 16);
    op[0] = ob.u[0];
    op[1] = ob.u[1];
}

extern "C" void kernel_launch(void* const* d_in, const int* in_sizes, int n_in,
                              void* d_out, int out_size, void* d_ws, size_t ws_size,
                              hipStream_t stream)
{
    const float* x      = (const float*)d_in[0];   // (4,56,56,256)
    const float* w_qkv  = (const float*)d_in[1];   // (256,768)
    const float* b_qkv  = (const float*)d_in[2];   // (768,)
    const float* rpb    = (const float*)d_in[3];   // (8,49)
    const float* w_proj = (const float*)d_in[4];   // (256,256)
    const float* b_proj = (const float*)d_in[5];   // (256,)
    float* out = (float*)d_out;                    // (4,56,56,256) fp32

    const int M = 12544;

    char* wsp = (char*)d_ws;
    float* qf = (float*)wsp;                      wsp += (size_t)M * 256 * 4;   // 12.85 MB
    __hip_bfloat16* kp    = (__hip_bfloat16*)wsp; wsp += (size_t)4 * 64 * 64 * 256 * 2; // 8.39 MB
    __hip_bfloat16* vp    = (__hip_bfloat16*)wsp; wsp += (size_t)4 * 64 * 64 * 256 * 2; // 8.39 MB
    __hip_bfloat16* xb    = (__hip_bfloat16*)wsp; wsp += (size_t)M * 256 * 2;
    __hip_bfloat16* attnb = (__hip_bfloat16*)wsp; wsp += (size_t)M * 256 * 2;
    __hip_bfloat16* wqkvT = (__hip_bfloat16*)wsp; wsp += (size_t)768 * 256 * 2;
    __hip_bfloat16* wprojT= (__hip_bfloat16*)wsp; wsp += (size_t)256 * 256 * 2;

    const float scale = 0.17677669529663689f;  // 32^-0.5

    // fused prep: x->bf16, both weight transposes, pad-border zero of kp/vp
    prep<<<5120, 256, 0, stream>>>(x, xb, w_qkv, wqkvT, w_proj, wprojT, kp, vp);

    // qkv = xb @ wqkvT^T + b_qkv; q fp32 scaled -> qf; k/v bf16 -> padded planes
    gemm_qkv<<<dim3(6, 98), 256, 0, stream>>>(xb, wqkvT, b_qkv, qf, kp, vp, scale);

    // attention: 3136 blocks x 64 threads, single-pass online softmax, rolled ky
    na2d_attn9<<<3136, 64, 0, stream>>>(qf, kp, vp, rpb, attnb);

    // out = attnb @ wprojT^T + b_proj (64-tile: 784 blocks ~= 3/CU)
    gemm_proj<<<dim3(4, 196), 256, 0, stream>>>(attnb, wprojT, b_proj, out);
}